// Round 1
// baseline (549.318 us; speedup 1.0000x reference)
//
#include <hip/hip_runtime.h>
#include <hip/hip_bf16.h>

// LSTM cell fused: gates = [x,h] @ W + b ; i=sig(i); nc=(1-i)*c+i*tanh(j);
// nh=tanh(nc)*sig(o). B=16384, IN=H=1024, K=2048, 3H=3072.
// Strategy: cast to bf16, MFMA GEMM (m97-style 128x64x3gates tile), fused epilogue.

#define B_DIM 16384
#define K_DIM 2048
#define H_DIM 1024

typedef __attribute__((ext_vector_type(8))) short short8;
typedef __attribute__((ext_vector_type(4))) short short4v;
typedef __attribute__((ext_vector_type(4))) float floatx4;

__device__ __forceinline__ short f2bf(float f) {
  unsigned u = __builtin_bit_cast(unsigned, f);
  u += 0x7fffu + ((u >> 16) & 1u);   // round-to-nearest-even
  return (short)(u >> 16);
}

__device__ __forceinline__ float sigm(float x) { return 1.f / (1.f + __expf(-x)); }
__device__ __forceinline__ float tanh_f(float x) {
  float e = __expf(2.f * x);
  return 1.f - 2.f / (e + 1.f);      // exact limits at +-inf
}

// ---------------- Kernel 1: concat(x,h) -> bf16 A [16384][2048] ----------------
__global__ __launch_bounds__(256) void concat_cast_kernel(
    const float* __restrict__ x, const float* __restrict__ h, short* __restrict__ A) {
  int t = blockIdx.x * 256 + threadIdx.x;
  int e = t * 8;                      // 8 elems per thread, total exactly covers
  int r = e >> 11;                    // row
  int k = e & 2047;                   // col in concat
  const float* src = (k < 1024) ? (x + r * 1024 + k) : (h + r * 1024 + (k - 1024));
  floatx4 v0 = *(const floatx4*)(src);
  floatx4 v1 = *(const floatx4*)(src + 4);
  short8 o;
  o[0] = f2bf(v0[0]); o[1] = f2bf(v0[1]); o[2] = f2bf(v0[2]); o[3] = f2bf(v0[3]);
  o[4] = f2bf(v1[0]); o[5] = f2bf(v1[1]); o[6] = f2bf(v1[2]); o[7] = f2bf(v1[3]);
  *(short8*)(A + e) = o;
}

// ---------------- Kernel 2: W [2048][3072] f32 -> Wt [3072][2048] bf16 ----------------
__global__ __launch_bounds__(256) void wtrans_kernel(
    const float* __restrict__ W, short* __restrict__ Wt) {
  __shared__ float t[64][65];         // +1 pad: conflict-free column reads
  int tid = threadIdx.x;
  int kt = blockIdx.x * 64;           // k-tile base (2048/64 = 32)
  int nt = blockIdx.y * 64;           // n-tile base (3072/64 = 48)
  int rr = tid >> 4;                  // 0..15
  int c4 = (tid & 15) * 4;            // 0..60
#pragma unroll
  for (int it = 0; it < 4; ++it) {
    int row = it * 16 + rr;
    floatx4 v = *(const floatx4*)&W[(long)(kt + row) * 3072 + nt + c4];
    t[row][c4 + 0] = v[0]; t[row][c4 + 1] = v[1];
    t[row][c4 + 2] = v[2]; t[row][c4 + 3] = v[3];
  }
  __syncthreads();
#pragma unroll
  for (int it = 0; it < 4; ++it) {
    int n_ = it * 16 + rr;
    short4v s;
    s[0] = f2bf(t[c4 + 0][n_]); s[1] = f2bf(t[c4 + 1][n_]);
    s[2] = f2bf(t[c4 + 2][n_]); s[3] = f2bf(t[c4 + 3][n_]);
    *(short4v*)&Wt[(long)(nt + n_) * 2048 + kt + c4] = s;
  }
}

// ---------------- Kernel 3: fused GEMM + LSTM epilogue ----------------
// Tile: BM=128 rows x BN=64 cols x 3 gates. BK=64. 256 threads (4 waves).
// Wave w owns rows [w*32, w*32+32): m_rep=2, n_rep=4, gates=3 -> 24 frags, 96 acc VGPRs.
#define BM 128
#define BN 64
#define BK 64

__device__ __forceinline__ void gload_lds16(const void* g, void* l) {
  __builtin_amdgcn_global_load_lds(
      (const __attribute__((address_space(1))) void*)g,
      (__attribute__((address_space(3))) void*)l, 16, 0, 0);
}

__global__ __launch_bounds__(256, 2) void lstm_gemm_kernel(
    const short* __restrict__ A, const short* __restrict__ Wt,
    const float* __restrict__ bias, const float* __restrict__ Cin,
    float* __restrict__ out) {
  __shared__ short As[BM * BK];        // 16 KB
  __shared__ short Ws[3][BN * BK];     // 24 KB
  const int tid = threadIdx.x;
  const int lane = tid & 63;
  const int wave = tid >> 6;
  const int m0 = blockIdx.x * BM;
  const int n0 = blockIdx.y * BN;
  const int lr = lane & 15;            // fragment row/col index
  const int lg = lane >> 4;            // k-group
  const int srow = tid >> 3;           // staging: 0..31
  const int scol = (tid & 7) * 8;      // staging: k-offset (x8 elems = 16B)

  floatx4 acc[3][2][4] = {};

  for (int k0 = 0; k0 < K_DIM; k0 += BK) {
    // stage A tile (128x64 bf16) : 4 issues x 256 lanes x 16B
#pragma unroll
    for (int it = 0; it < 4; ++it) {
      int r = it * 32 + srow;
      gload_lds16(A + (long)(m0 + r) * K_DIM + k0 + scol, As + r * BK + scol);
    }
    // stage 3 W tiles (64x64 bf16 each) : 2 issues each
#pragma unroll
    for (int g = 0; g < 3; ++g) {
#pragma unroll
      for (int it = 0; it < 2; ++it) {
        int r = it * 32 + srow;
        gload_lds16(Wt + (long)(g * 1024 + n0 + r) * K_DIM + k0 + scol,
                    Ws[g] + r * BK + scol);
      }
    }
    __syncthreads();   // compiler drains vmcnt before barrier

#pragma unroll
    for (int kk = 0; kk < BK; kk += 32) {
      short8 af[2];
#pragma unroll
      for (int mr = 0; mr < 2; ++mr)
        af[mr] = *(const short8*)&As[(wave * 32 + mr * 16 + lr) * BK + kk + lg * 8];
#pragma unroll
      for (int g = 0; g < 3; ++g) {
#pragma unroll
        for (int nr = 0; nr < 4; ++nr) {
          short8 bf = *(const short8*)&Ws[g][(nr * 16 + lr) * BK + kk + lg * 8];
#pragma unroll
          for (int mr = 0; mr < 2; ++mr)
            acc[g][mr][nr] = __builtin_amdgcn_mfma_f32_16x16x32_bf16(
                af[mr], bf, acc[g][mr][nr], 0, 0, 0);
        }
      }
    }
    __syncthreads();
  }

  // Epilogue: D mapping row=(lane>>4)*4+reg, col=lane&15 (m89-verified)
  const float* bi = bias;
  const float* bj = bias + 1024;
  const float* bo = bias + 2048;
#pragma unroll
  for (int mr = 0; mr < 2; ++mr) {
#pragma unroll
    for (int nr = 0; nr < 4; ++nr) {
      int col = n0 + nr * 16 + lr;
      float vbi = bi[col], vbj = bj[col], vbo = bo[col];
#pragma unroll
      for (int r = 0; r < 4; ++r) {
        int row = m0 + wave * 32 + mr * 16 + lg * 4 + r;
        float xi = acc[0][mr][nr][r] + vbi;
        float xj = acc[1][mr][nr][r] + vbj;
        float xo = acc[2][mr][nr][r] + vbo;
        float ii = sigm(xi);
        float tj = tanh_f(xj);
        float oc = Cin[(long)row * H_DIM + col];
        float nc = (1.f - ii) * oc + ii * tj;
        float nh = tanh_f(nc) * sigm(xo);
        long oidx = (long)row * H_DIM + col;
        out[oidx] = nh;
        out[(long)B_DIM * H_DIM + oidx] = nc;
      }
    }
  }
}

// ---------------- Fallback (ws too small): naive fp32, correctness-only ----------------
__global__ __launch_bounds__(256) void lstm_naive_kernel(
    const float* __restrict__ x, const float* __restrict__ h,
    const float* __restrict__ c, const float* __restrict__ W,
    const float* __restrict__ b, float* __restrict__ out) {
  long idx = (long)blockIdx.x * 256 + threadIdx.x;
  if (idx >= (long)B_DIM * H_DIM) return;
  int row = (int)(idx >> 10), col = (int)(idx & 1023);
  float si = b[col], sj = b[1024 + col], so = b[2048 + col];
  const float* xr = x + (long)row * 1024;
  const float* hr = h + (long)row * 1024;
  for (int k = 0; k < 1024; ++k) {
    float a = xr[k];
    const float* wr = W + (long)k * 3072 + col;
    si += a * wr[0]; sj += a * wr[1024]; so += a * wr[2048];
  }
  for (int k = 0; k < 1024; ++k) {
    float a = hr[k];
    const float* wr = W + (long)(1024 + k) * 3072 + col;
    si += a * wr[0]; sj += a * wr[1024]; so += a * wr[2048];
  }
  float ii = sigm(si);
  float tj = tanh_f(sj);
  float oc = c[idx];
  float nc = (1.f - ii) * oc + ii * tj;
  out[idx] = tanh_f(nc) * sigm(so);
  out[(long)B_DIM * H_DIM + idx] = nc;
}

extern "C" void kernel_launch(void* const* d_in, const int* in_sizes, int n_in,
                              void* d_out, int out_size, void* d_ws, size_t ws_size,
                              hipStream_t stream) {
  const float* x = (const float*)d_in[0];
  const float* h = (const float*)d_in[1];
  const float* c = (const float*)d_in[2];
  const float* W = (const float*)d_in[3];
  const float* b = (const float*)d_in[4];
  float* out = (float*)d_out;

  const size_t A_elems = (size_t)B_DIM * K_DIM;       // 33,554,432
  const size_t Wt_elems = (size_t)3072 * K_DIM;       //  6,291,456
  const size_t needed = (A_elems + Wt_elems) * 2;     // ~76 MiB

  if (ws_size < needed) {
    lstm_naive_kernel<<<(B_DIM * H_DIM) / 256, 256, 0, stream>>>(x, h, c, W, b, out);
    return;
  }

  short* Abf = (short*)d_ws;
  short* Wtb = Abf + A_elems;

  concat_cast_kernel<<<(B_DIM * K_DIM) / (256 * 8), 256, 0, stream>>>(x, h, Abf);
  wtrans_kernel<<<dim3(32, 48), 256, 0, stream>>>(W, Wtb);
  lstm_gemm_kernel<<<dim3(B_DIM / BM, H_DIM / BN), 256, 0, stream>>>(Abf, Wtb, b, c, out);
}